// Round 11
// baseline (440.043 us; speedup 1.0000x reference)
//
#include <hip/hip_runtime.h>
#include <hip/hip_bf16.h>

using f32x4  = __attribute__((ext_vector_type(4))) float;
using bf16x8 = __attribute__((ext_vector_type(8))) short;

__device__ __forceinline__ unsigned short f2bf(float f) {
    union { __hip_bfloat16 h; unsigned short u; } cv;
    cv.h = __float2bfloat16(f);
    return cv.u;
}
__device__ __forceinline__ unsigned int pack2bf(float lo, float hi) {
    float2 t; t.x = lo; t.y = hi;
    union { __hip_bfloat162 h; unsigned int u; } cv;
    cv.h = __float22bfloat162_rn(t);
    return cv.u;
}
__device__ __forceinline__ float bf2f(unsigned short u) {
    return __uint_as_float((unsigned)u << 16);
}

// ---------------- prep: converts / packs (source-coalesced reads) ----------------
__global__ __launch_bounds__(512) void prep_kernel(
        const float* __restrict__ E, const float* __restrict__ Wsc0, const float* __restrict__ Wsc1,
        const float* __restrict__ Wfw, const float* __restrict__ bfw,
        const float* __restrict__ Wbw, const float* __restrict__ bbw,
        const float* __restrict__ Wlin,
        unsigned short* __restrict__ E16, unsigned short* __restrict__ W0p,
        unsigned short* __restrict__ WabP,
        unsigned short* __restrict__ WcatT, unsigned short* __restrict__ WlinT,
        float* __restrict__ bsumS, unsigned short* __restrict__ W1p) {
    const int NE = 131072, NW0 = 131072, NWAB = 262144, NCAT = 524288, NLIN = 131072, NW1P = 8192;
    const int total = NE + NW0 + NWAB + NCAT + NLIN + NW1P + 512;
    for (int idx = blockIdx.x * 512 + threadIdx.x; idx < total; idx += 512 * 512) {
        int t = idx;
        if (t < NE) { E16[t] = f2bf(E[t]); continue; }
        t -= NE;
        if (t < NW0) {
            int k = t >> 9, f = t & 511;
            int w = f >> 6, nb = (f >> 4) & 3, l15 = f & 15;
            int kk = k >> 5, l4 = (k >> 3) & 3, e = k & 7;
            W0p[((((w * 4 + nb) * 8 + kk) * 64) + l4 * 16 + l15) * 8 + e] = f2bf(Wsc0[(512 + k) * 512 + f]);
            continue;
        }
        t -= NW0;
        if (t < NWAB) {
            int r = t >> 9, col = t & 511;
            int k = r & 255;
            int fcol = (r < 256) ? col : (512 + col);
            int wf = fcol >> 6, nb = (fcol >> 4) & 3, l15 = fcol & 15;
            int kk = k >> 5, l4 = (k >> 3) & 3, e = k & 7;
            WabP[((((wf * 4 + nb) * 8 + kk) * 64) + l4 * 16 + l15) * 8 + e] = f2bf(Wsc0[r * 512 + col]);
            continue;
        }
        t -= NWAB;
        if (t < NCAT) {
            int e = t & 127, k = (t >> 7) & 255, r = (t >> 15) & 3, d = (t >> 17) & 1, l = t >> 18;
            const float* src = (d == 0) ? Wfw : Wbw;
            float v = src[((l * 4 + r) * 256 + k) * 128 + e];
            WcatT[(l * 1024 + d * 512 + r * 128 + e) * 256 + k] = f2bf(v);
            continue;
        }
        t -= NCAT;
        if (t < NLIN) {
            int d = t & 255, f = (t >> 8) & 255, l = t >> 16;
            WlinT[(l * 256 + d) * 256 + f] = f2bf(Wlin[(l * 256 + f) * 256 + d]);
            continue;
        }
        t -= NLIN;
        if (t < NW1P) {
            int e = t & 7, lane = (t >> 3) & 63, kap = t >> 9;
            int fp = kap * 32 + (lane >> 4) * 8 + e;
            int w = fp >> 6, q = (fp >> 2) & 15, nb = fp & 3;
            int f = w * 64 + nb * 16 + q;
            int r = lane & 15;
            W1p[t] = (r < 4) ? f2bf(Wsc1[f * 4 + r]) : (unsigned short)0;
            continue;
        }
        t -= NW1P;
        {
            int f = t & 255, l = t >> 8;
            float s = 0.f;
            if (f < 128) { for (int r = 0; r < 4; ++r) s += bbw[(l * 4 + r) * 128 + f]; }
            else         { for (int r = 0; r < 4; ++r) s += bfw[(l * 4 + r) * 128 + (f - 128)]; }
            bsumS[l * 256 + f] = s;
        }
    }
}

// ---------------- uv: U=E@W0a (+b0, nb-paired pack), V=E@W0b (fp32 row-major) via MFMA ----------------
__global__ __launch_bounds__(512) void uv_kernel(const unsigned short* __restrict__ E16,
                                                 const unsigned short* __restrict__ WabP,
                                                 const float* __restrict__ bsc0,
                                                 unsigned short* __restrict__ Upk,
                                                 float* __restrict__ V) {
    __shared__ unsigned short sE[32 * 256];
    const int jt = blockIdx.x;
    const int tid = threadIdx.x, lane = tid & 63, w = tid >> 6;
    const int l15 = lane & 15, l4 = lane >> 4;
#pragma unroll
    for (int it = 0; it < 2; ++it) {
        int u = it * 512 + tid;
        int row = u >> 5, slot = u & 31;
        uint4 v = *(const uint4*)(E16 + (jt * 32 + row) * 256 + slot * 8);
        *(uint4*)((char*)sE + row * 512 + ((slot * 16) ^ ((row & 7) << 4))) = v;
    }
    __syncthreads();
    const bf16x8* Wab8 = (const bf16x8*)WabP;
    f32x4 acc[2][8];
#pragma unroll
    for (int a_ = 0; a_ < 2; ++a_)
#pragma unroll
        for (int b_ = 0; b_ < 8; ++b_) acc[a_][b_] = (f32x4){0.f, 0.f, 0.f, 0.f};
#pragma unroll
    for (int kk = 0; kk < 8; ++kk) {
        bf16x8 af[2];
#pragma unroll
        for (int mbl = 0; mbl < 2; ++mbl) {
            int row = mbl * 16 + l15;
            af[mbl] = *(const bf16x8*)((char*)sE + row * 512 + ((kk * 64 + l4 * 16) ^ ((row & 7) << 4)));
        }
#pragma unroll
        for (int nb = 0; nb < 8; ++nb) {
            int wf = 2 * w + (nb >> 2);
            bf16x8 bfr = Wab8[((wf * 4 + (nb & 3)) * 8 + kk) * 64 + lane];
#pragma unroll
            for (int mbl = 0; mbl < 2; ++mbl)
                acc[mbl][nb] = __builtin_amdgcn_mfma_f32_16x16x32_bf16(af[mbl], bfr, acc[mbl][nb], 0, 0, 0);
        }
    }
#pragma unroll
    for (int mbl = 0; mbl < 2; ++mbl) {
        int j_base = jt * 32 + mbl * 16 + l4 * 4;
#pragma unroll
        for (int nb8 = 0; nb8 < 8; ++nb8) {
            int f_g = (2 * w + (nb8 >> 2)) * 64 + (nb8 & 3) * 16 + l15;
            if (f_g < 512) {
                float b0f = bsc0[f_g];
                ushort4 o;
                o.x = f2bf(acc[mbl][nb8][0] + b0f);
                o.y = f2bf(acc[mbl][nb8][1] + b0f);
                o.z = f2bf(acc[mbl][nb8][2] + b0f);
                o.w = f2bf(acc[mbl][nb8][3] + b0f);
                int jtp = j_base >> 6, mbp = (j_base >> 4) & 3;
                int wp = f_g >> 6, nbp = (f_g >> 4) & 3;
                int lanep = l4 * 16 + l15;
                *(ushort4*)(Upk + ((((jtp * 8 + wp) * 4 + mbp) * 2 + (nbp >> 1)) * 64 + lanep) * 8 + (nbp & 1) * 4) = o;
            } else {
                int fv = f_g - 512;
#pragma unroll
                for (int reg = 0; reg < 4; ++reg)
                    V[(j_base + reg) * 512 + fv] = acc[mbl][nb8][reg];
            }
        }
    }
}

// ---------------- pair scorer (R7 structure), templated for ablation ----------------
// MODE 0: full.  1: no prod staging.  2: A-frags constant (no ds_read stream).
// 3: B-frags constant (no W0p L2 stream).
template<int MODE>
__global__ __launch_bounds__(512, 2) void pair_kernel(
    const unsigned short* __restrict__ E16, const unsigned short* __restrict__ W0p,
    const unsigned short* __restrict__ Upk, const float* __restrict__ V,
    const unsigned short* __restrict__ W1p, const float* __restrict__ b1,
    unsigned short* __restrict__ outA) {

    __shared__ unsigned short bufL[2 * 64 * 256];
    __shared__ float vrow[2][512];
    __shared__ float scoresL[2][256];

    const int i0 = blockIdx.x * 2, i1 = i0 + 1;
    const int jt = blockIdx.y;
    const int j0 = jt * 64;
    const int tid = threadIdx.x;
    const int lane = tid & 63;
    const int w = tid >> 6;
    const int l15 = lane & 15, l4 = lane >> 4;

    uint4 uq[4][2];
#pragma unroll
    for (int mb = 0; mb < 4; ++mb)
#pragma unroll
        for (int nbh = 0; nbh < 2; ++nbh)
            uq[mb][nbh] = *(const uint4*)(Upk + ((((jt * 8 + w) * 4 + mb) * 2 + nbh) * 64 + lane) * 8);
    vrow[0][tid] = V[i0 * 512 + tid];
    vrow[1][tid] = V[i1 * 512 + tid];
    if (tid < 256) { scoresL[0][tid] = b1[tid & 3]; scoresL[1][tid] = b1[tid & 3]; }

    if constexpr (MODE != 1) {
        int m = tid >> 3;
        int s = tid & 7;
        const bf16x8* ejp  = (const bf16x8*)(E16 + (j0 + m) * 256 + s * 8);
        const bf16x8* ei0p = (const bf16x8*)(E16 + i0 * 256 + s * 8);
        const bf16x8* ei1p = (const bf16x8*)(E16 + i1 * 256 + s * 8);
        char* base = (char*)bufL;
#pragma unroll
        for (int c = 0; c < 4; ++c) {
            bf16x8 ej = ejp[c * 8], e0 = ei0p[c * 8], e1 = ei1p[c * 8];
            uint4 v0, v1;
            unsigned* p0 = (unsigned*)&v0;
            unsigned* p1 = (unsigned*)&v1;
#pragma unroll
            for (int e2 = 0; e2 < 4; ++e2) {
                float jl = bf2f((unsigned short)ej[e2 * 2]), jh = bf2f((unsigned short)ej[e2 * 2 + 1]);
                p0[e2] = pack2bf(jl * bf2f((unsigned short)e0[e2 * 2]), jh * bf2f((unsigned short)e0[e2 * 2 + 1]));
                p1[e2] = pack2bf(jl * bf2f((unsigned short)e1[e2 * 2]), jh * bf2f((unsigned short)e1[e2 * 2 + 1]));
            }
            int off = m * 512 + ((s * 16 + c * 128) ^ ((m & 7) << 4));
            *(uint4*)(base + off) = v0;
            *(uint4*)(base + 32768 + off) = v1;
        }
    }

    f32x4 acc0[4][4], acc1[4][4];
#pragma unroll
    for (int mb = 0; mb < 4; ++mb)
#pragma unroll
        for (int nbh = 0; nbh < 2; ++nbh) {
            const unsigned short* us = (const unsigned short*)&uq[mb][nbh];
#pragma unroll
            for (int h = 0; h < 2; ++h) {
                int nb = nbh * 2 + h;
                float v0f = vrow[0][w * 64 + nb * 16 + l15];
                float v1f = vrow[1][w * 64 + nb * 16 + l15];
#pragma unroll
                for (int reg = 0; reg < 4; ++reg) {
                    float uu = bf2f(us[h * 4 + reg]);
                    acc0[mb][nb][reg] = uu + v0f;
                    acc1[mb][nb][reg] = uu + v1f;
                }
            }
        }
    __syncthreads();

    const char* pbase = (const char*)bufL;
    const bf16x8* Wp8 = (const bf16x8*)W0p;
    const bf16x8 cfr = {0x3f80, 0x3f80, 0x3f80, 0x3f80, 0x3f80, 0x3f80, 0x3f80, 0x3f80};
#pragma unroll
    for (int kk = 0; kk < 8; ++kk) {
        bf16x8 bfr[4];
#pragma unroll
        for (int nb = 0; nb < 4; ++nb) {
            if constexpr (MODE == 3) bfr[nb] = cfr;
            else bfr[nb] = Wp8[((w * 4 + nb) * 8 + kk) * 64 + lane];
        }
        bf16x8 afr[4];
#pragma unroll
        for (int mb = 0; mb < 4; ++mb) {
            if constexpr (MODE == 2) afr[mb] = cfr;
            else {
                int row = mb * 16 + l15;
                afr[mb] = *(const bf16x8*)(pbase + row * 512 + ((kk * 64 + l4 * 16) ^ ((row & 7) << 4)));
            }
        }
#pragma unroll
        for (int mb = 0; mb < 4; ++mb)
#pragma unroll
            for (int nb = 0; nb < 4; ++nb)
                acc0[mb][nb] = __builtin_amdgcn_mfma_f32_16x16x32_bf16(afr[mb], bfr[nb], acc0[mb][nb], 0, 0, 0);
#pragma unroll
        for (int mb = 0; mb < 4; ++mb) {
            if constexpr (MODE == 2) afr[mb] = cfr;
            else {
                int row = mb * 16 + l15;
                afr[mb] = *(const bf16x8*)(pbase + 32768 + row * 512 + ((kk * 64 + l4 * 16) ^ ((row & 7) << 4)));
            }
        }
#pragma unroll
        for (int mb = 0; mb < 4; ++mb)
#pragma unroll
            for (int nb = 0; nb < 4; ++nb)
                acc1[mb][nb] = __builtin_amdgcn_mfma_f32_16x16x32_bf16(afr[mb], bfr[nb], acc1[mb][nb], 0, 0, 0);
    }
    __syncthreads();

    // ---- epilogue per i ----
    char* hb = (char*)bufL;
    const bf16x8* W1p8 = (const bf16x8*)W1p;
    bf16x8 w1f[2];
#pragma unroll
    for (int kl = 0; kl < 2; ++kl) w1f[kl] = W1p8[(w * 2 + kl) * 64 + lane];

#pragma unroll
    for (int ii = 0; ii < 2; ++ii) {
#pragma unroll
        for (int mb = 0; mb < 4; ++mb)
#pragma unroll
            for (int reg = 0; reg < 4; ++reg) {
                int rl = mb * 16 + l4 * 4 + reg;
                f32x4* A = (ii == 0) ? &acc0[mb][0] : &acc1[mb][0];
                float h0 = fmaxf(A[0][reg], 0.f);
                float h1 = fmaxf(A[1][reg], 0.f);
                float h2 = fmaxf(A[2][reg], 0.f);
                float h3 = fmaxf(A[3][reg], 0.f);
                uint2 val;
                val.x = pack2bf(h0, h1);
                val.y = pack2bf(h2, h3);
                *(uint2*)(hb + rl * 1024 + ((w * 128 + l15 * 8) ^ ((rl & 7) << 4))) = val;
            }
        __syncthreads();
        f32x4 accS[4];
#pragma unroll
        for (int mb = 0; mb < 4; ++mb) {
            accS[mb] = (f32x4){0.f, 0.f, 0.f, 0.f};
            int rl = mb * 16 + l15;
#pragma unroll
            for (int kl = 0; kl < 2; ++kl) {
                bf16x8 ha = *(const bf16x8*)(hb + rl * 1024 + (((w * 2 + kl) * 64 + l4 * 16) ^ ((rl & 7) << 4)));
                accS[mb] = __builtin_amdgcn_mfma_f32_16x16x32_bf16(ha, w1f[kl], accS[mb], 0, 0, 0);
            }
        }
        if (l15 < 4) {
#pragma unroll
            for (int mb = 0; mb < 4; ++mb)
#pragma unroll
                for (int reg = 0; reg < 4; ++reg)
                    atomicAdd(&scoresL[ii][(mb * 16 + l4 * 4 + reg) * 4 + l15], accS[mb][reg]);
        }
        __syncthreads();
    }

    if (tid < 128) {
        int ii = tid >> 6, m = tid & 63;
        int j = j0 + m, ic = i0 + ii;
        float s0 = scoresL[ii][m * 4 + 0], s1 = scoresL[ii][m * 4 + 1];
        float sA = scoresL[ii][m * 4 + 2], sB = scoresL[ii][m * 4 + 3];
        float mx = fmaxf(fmaxf(s0, s1), fmaxf(sA, sB));
        float e0 = __expf(s0 - mx), e1 = __expf(s1 - mx), e2 = __expf(sA - mx), e3 = __expf(sB - mx);
        float inv = 1.f / (e0 + e1 + e2 + e3);
        float p_[4] = {e0 * inv, e1 * inv, e2 * inv, e3 * inv};
        if (j == ic) { p_[0] = p_[1] = p_[2] = p_[3] = 0.f; }
#pragma unroll
        for (int r = 0; r < 4; ++r)
            outA[(r * 512 + ic) * 512 + j] = f2bf(p_[r]);
    }
}

// ---------------- LDS panel helpers ----------------
template<int K>
__device__ __forceinline__ void stageP(unsigned short* lds, const unsigned short* g, int ldg, int tid) {
    constexpr int SLOTS = K / 8;
#pragma unroll
    for (int it = 0; it < (32 * SLOTS) / 256; ++it) {
        int u = it * 256 + tid;
        int row = u / SLOTS, slot = u % SLOTS;
        uint4 v = *(const uint4*)(g + row * ldg + slot * 8);
        *(uint4*)((char*)lds + row * (K * 2) + ((slot * 16) ^ ((row & 7) << 4))) = v;
    }
}
__device__ __forceinline__ void stage64(unsigned short* lds, const unsigned short* g, int ldg, int tid) {
#pragma unroll
    for (int it = 0; it < 8; ++it) {
        int u = it * 256 + tid;
        int row = u >> 5, slot = u & 31;
        uint4 v = *(const uint4*)(g + row * ldg + slot * 8);
        *(uint4*)((char*)lds + row * 512 + ((slot * 16) ^ ((row & 7) << 4))) = v;
    }
}
template<int K>
__device__ __forceinline__ bf16x8 fragP(const unsigned short* lds, int row, int kc, int l4) {
    return *(const bf16x8*)((const char*)lds + row * (K * 2) + ((((kc * 4 + l4) * 16) ^ ((row & 7) << 4))));
}

// ---------------- c1 ----------------
__global__ __launch_bounds__(256) void c1_kernel(const unsigned short* __restrict__ WcatT,
                                                 const unsigned short* __restrict__ x16,
                                                 unsigned short* __restrict__ supT,
                                                 const unsigned short* __restrict__ A16,
                                                 unsigned short* __restrict__ AT16, int l) {
    __shared__ unsigned short lA[32 * 256], lB[32 * 256];
    int tid = threadIdx.x;
    if (blockIdx.y >= 16) {
        auto t = (unsigned short(*)[65])lA;
        int job = (blockIdx.y - 16) * 32 + blockIdx.x;
        int r = job >> 6, ty = (job >> 3) & 7, tx = job & 7;
        const unsigned short* src = A16 + (r * 512 + ty * 64) * 512 + tx * 64;
        unsigned short* dst = AT16 + (r * 512 + tx * 64) * 512 + ty * 64;
#pragma unroll
        for (int it = 0; it < 2; ++it) {
            int u = it * 256 + tid, row = u >> 3, c8 = (u & 7) * 8;
            uint4 v = *(const uint4*)(src + row * 512 + c8);
            const unsigned short* p = (const unsigned short*)&v;
#pragma unroll
            for (int e = 0; e < 8; ++e) t[c8 + e][row] = p[e];
        }
        __syncthreads();
#pragma unroll
        for (int it = 0; it < 2; ++it) {
            int u = it * 256 + tid, row = u >> 3, c8 = (u & 7) * 8;
            uint4 v; unsigned short* p = (unsigned short*)&v;
#pragma unroll
            for (int e = 0; e < 8; ++e) p[e] = t[row][c8 + e];
            *(uint4*)(dst + row * 512 + c8) = v;
        }
        return;
    }
    int c0 = blockIdx.x * 32, jt0 = blockIdx.y * 32;
    int lane = tid & 63, w = tid >> 6;
    int wr = (w >> 1) * 16, wc = (w & 1) * 16;
    int l15 = lane & 15, l4 = lane >> 4;
    stageP<256>(lA, WcatT + l * 262144 + c0 * 256, 256, tid);
    stageP<256>(lB, x16 + jt0 * 256, 256, tid);
    __syncthreads();
    f32x4 a0 = {0.f,0.f,0.f,0.f}, a1 = {0.f,0.f,0.f,0.f};
#pragma unroll
    for (int kc = 0; kc < 8; kc += 2) {
        a0 = __builtin_amdgcn_mfma_f32_16x16x32_bf16(fragP<256>(lA, wr + l15, kc, l4),
                                                     fragP<256>(lB, wc + l15, kc, l4), a0, 0, 0, 0);
        a1 = __builtin_amdgcn_mfma_f32_16x16x32_bf16(fragP<256>(lA, wr + l15, kc + 1, l4),
                                                     fragP<256>(lB, wc + l15, kc + 1, l4), a1, 0, 0, 0);
    }
    f32x4 acc = a0 + a1;
#pragma unroll
    for (int reg = 0; reg < 4; ++reg) {
        int c = c0 + wr + l4 * 4 + reg;
        int j = jt0 + wc + l15;
        supT[c * 512 + j] = f2bf(acc[reg]);
    }
}

// ---------------- c2 (split-k) ----------------
__global__ __launch_bounds__(256) void c2_kernel(const unsigned short* __restrict__ A16,
                                                 const unsigned short* __restrict__ AT16,
                                                 const unsigned short* __restrict__ supT,
                                                 float* __restrict__ Pc2) {
    __shared__ unsigned short lA[64 * 256], lB[64 * 256];
    int i0 = blockIdx.x * 64, f0 = blockIdx.y * 64;
    int s = blockIdx.z, r = s >> 1, kh = s & 1;
    bool bw = (f0 < 128);
    int e0 = bw ? f0 : (f0 - 128);
    const unsigned short* Am = bw ? AT16 : A16;
    int tid = threadIdx.x, lane = tid & 63, w = tid >> 6;
    int wr = (w >> 1) * 32, wc = (w & 1) * 32;
    int l15 = lane & 15, l4 = lane >> 4;
    stage64(lA, Am + (r * 512 + i0) * 512 + kh * 256, 512, tid);
    stage64(lB, supT + ((bw ? 512 : 0) + r * 128 + e0) * 512 + kh * 256, 512, tid);
    __syncthreads();
    f32x4 acc[2][2];
#pragma unroll
    for (int a_ = 0; a_ < 2; ++a_)
#pragma unroll
        for (int b_ = 0; b_ < 2; ++b_) acc[a_][b_] = (f32x4){0.f, 0.f, 0.f, 0.f};
#pragma unroll
    for (int kc = 0; kc < 8; ++kc) {
        bf16x8 af[2], bf_[2];
#pragma unroll
        for (int mb = 0; mb < 2; ++mb) af[mb] = fragP<256>(lA, wr + mb * 16 + l15, kc, l4);
#pragma unroll
        for (int nb = 0; nb < 2; ++nb) bf_[nb] = fragP<256>(lB, wc + nb * 16 + l15, kc, l4);
#pragma unroll
        for (int mb = 0; mb < 2; ++mb)
#pragma unroll
            for (int nb = 0; nb < 2; ++nb)
                acc[mb][nb] = __builtin_amdgcn_mfma_f32_16x16x32_bf16(af[mb], bf_[nb], acc[mb][nb], 0, 0, 0);
    }
    float* dst = Pc2 + s * 131072;
#pragma unroll
    for (int mb = 0; mb < 2; ++mb)
#pragma unroll
        for (int nb = 0; nb < 2; ++nb)
#pragma unroll
            for (int reg = 0; reg < 4; ++reg)
                dst[(i0 + wr + mb * 16 + l4 * 4 + reg) * 256 + f0 + wc + nb * 16 + l15] = acc[mb][nb][reg];
}

// ---------------- c3 ----------------
__global__ __launch_bounds__(256) void c3_kernel(const float* __restrict__ Pc2,
                                                 const float* __restrict__ bsumS,
                                                 const unsigned short* __restrict__ WlinT,
                                                 const float* __restrict__ blin,
                                                 const float* __restrict__ xold,
                                                 float* __restrict__ xnew,
                                                 unsigned short* __restrict__ x16out, int l) {
    __shared__ unsigned short lA[32 * 256], lB[32 * 256];
    int i0 = blockIdx.x * 32, d0 = blockIdx.y * 32;
    int tid = threadIdx.x, lane = tid & 63, w = tid >> 6;
    int wr = (w >> 1) * 16, wc = (w & 1) * 16;
    int l15 = lane & 15, l4 = lane >> 4;
#pragma unroll
    for (int g = 0; g < 4; ++g) {
        int u = g * 256 + tid;
        int row = u >> 5, k8 = (u & 31) * 8;
        float s[8] = {0,0,0,0,0,0,0,0};
#pragma unroll
        for (int s8 = 0; s8 < 8; ++s8) {
            const float4* p = (const float4*)(Pc2 + s8 * 131072 + (i0 + row) * 256 + k8);
            float4 a = p[0], b = p[1];
            s[0] += a.x; s[1] += a.y; s[2] += a.z; s[3] += a.w;
            s[4] += b.x; s[5] += b.y; s[6] += b.z; s[7] += b.w;
        }
        uint4 v;
        unsigned* vp = (unsigned*)&v;
#pragma unroll
        for (int e2 = 0; e2 < 4; ++e2) {
            float lo = fmaxf(s[e2 * 2] + bsumS[l * 256 + k8 + e2 * 2], 0.f);
            float hi = fmaxf(s[e2 * 2 + 1] + bsumS[l * 256 + k8 + e2 * 2 + 1], 0.f);
            vp[e2] = pack2bf(lo, hi);
        }
        *(uint4*)((char*)lA + row * 512 + ((k8 * 2) ^ ((row & 7) << 4))) = v;
    }
    stageP<256>(lB, WlinT + l * 65536 + d0 * 256, 256, tid);
    __syncthreads();
    f32x4 a0 = {0.f,0.f,0.f,0.f}, a1 = {0.f,0.f,0.f,0.f};
#pragma unroll
    for (int kc = 0; kc < 8; kc += 2) {
        a0 = __builtin_amdgcn_mfma_f32_16x16x32_bf16(fragP<256>(lA, wr + l15, kc, l4),
                                                     fragP<256>(lB, wc + l15, kc, l4), a0, 0, 0, 0);
        a1 = __builtin_amdgcn_mfma_f32_16x16x32_bf16(fragP<256>(lA, wr + l15, kc + 1, l4),
                                                     fragP<256>(lB, wc + l15, kc + 1, l4), a1, 0, 0, 0);
    }
    f32x4 acc = a0 + a1;
#pragma unroll
    for (int reg = 0; reg < 4; ++reg) {
        int ii = i0 + wr + l4 * 4 + reg;
        int dd = d0 + wc + l15;
        float vv = acc[reg] + blin[l * 256 + dd] + xold[ii * 256 + dd];
        xnew[ii * 256 + dd] = vv;
        x16out[ii * 256 + dd] = f2bf(vv);
    }
}

extern "C" void kernel_launch(void* const* d_in, const int* in_sizes, int n_in,
                              void* d_out, int out_size, void* d_ws, size_t ws_size,
                              hipStream_t stream) {
    const float* E    = (const float*)d_in[0];
    const float* Wsc0 = (const float*)d_in[1];
    const float* bsc0 = (const float*)d_in[2];
    const float* Wsc1 = (const float*)d_in[3];
    const float* bsc1 = (const float*)d_in[4];
    const float* Wfw  = (const float*)d_in[5];
    const float* bfw  = (const float*)d_in[6];
    const float* Wbw  = (const float*)d_in[7];
    const float* bbw  = (const float*)d_in[8];
    const float* Wlin = (const float*)d_in[9];
    const float* blin = (const float*)d_in[10];
    float* out = (float*)d_out;

    char* ws = (char*)d_ws;
    size_t off = 0;
    unsigned short* E16   = (unsigned short*)(ws + off); off += 512 * 256 * 2;
    unsigned short* W0p   = (unsigned short*)(ws + off); off += 512 * 256 * 2;
    unsigned short* WabP  = (unsigned short*)(ws + off); off += 1024 * 256 * 2;
    unsigned short* WcatT = (unsigned short*)(ws + off); off += 2 * 1024 * 256 * 2;
    unsigned short* WlinT = (unsigned short*)(ws + off); off += 2 * 256 * 256 * 2;
    float* bsumS          = (float*)(ws + off);          off += 2 * 256 * 4;
    unsigned short* Upk   = (unsigned short*)(ws + off); off += 512 * 512 * 2;
    float* V              = (float*)(ws + off);          off += 512 * 512 * 4;
    unsigned short* W1p   = (unsigned short*)(ws + off); off += 16 * 64 * 8 * 2;
    unsigned short* A16   = (unsigned short*)(ws + off); off += 4 * 512 * 512 * 2;
    unsigned short* AT16  = (unsigned short*)(ws + off); off += 4 * 512 * 512 * 2;
    unsigned short* supT  = (unsigned short*)(ws + off); off += 1024 * 512 * 2;
    // Pc2 doubles as the ablation dummy sink (fully overwritten by c2 before c3 reads)
    float* Pc2            = (float*)(ws + off);          off += 8 * 512 * 256 * 4;
    unsigned short* dumA  = (unsigned short*)Pc2;
    float* xf1            = (float*)(ws + off);          off += 512 * 256 * 4;
    unsigned short* x16_1 = (unsigned short*)(ws + off); off += 512 * 256 * 2;

    prep_kernel<<<512, 512, 0, stream>>>(E, Wsc0, Wsc1, Wfw, bfw, Wbw, bbw, Wlin,
                                         E16, W0p, WabP, WcatT, WlinT, bsumS, W1p);
    uv_kernel<<<16, 512, 0, stream>>>(E16, WabP, bsc0, Upk, V);

    // real pair (full grid, correct A16)
    pair_kernel<0><<<dim3(256, 8), 512, 0, stream>>>(E16, W0p, Upk, V, W1p, bsc1, A16);

    // ablation probes (half grid, dummy sink): V0h baseline, V1 nostage, V2 noAread, V3 noBload
    pair_kernel<0><<<dim3(256, 4), 512, 0, stream>>>(E16, W0p, Upk, V, W1p, bsc1, dumA);
    pair_kernel<1><<<dim3(256, 4), 512, 0, stream>>>(E16, W0p, Upk, V, W1p, bsc1, dumA);
    pair_kernel<2><<<dim3(256, 4), 512, 0, stream>>>(E16, W0p, Upk, V, W1p, bsc1, dumA);
    pair_kernel<3><<<dim3(256, 4), 512, 0, stream>>>(E16, W0p, Upk, V, W1p, bsc1, dumA);

    for (int l = 0; l < 2; ++l) {
        const unsigned short* xin16 = (l == 0) ? E16 : x16_1;
        const float* xoldf = (l == 0) ? E : xf1;
        float* xout = (l == 0) ? xf1 : out;
        c1_kernel<<<dim3(32, (l == 0) ? 24 : 16), 256, 0, stream>>>(WcatT, xin16, supT, A16, AT16, l);
        c2_kernel<<<dim3(8, 4, 8), 256, 0, stream>>>(A16, AT16, supT, Pc2);
        c3_kernel<<<dim3(16, 8), 256, 0, stream>>>(Pc2, bsumS, WlinT, blin, xoldf, xout, x16_1, l);
    }
    (void)in_sizes; (void)n_in; (void)out_size; (void)ws_size;
}

// Round 12
// 191.641 us; speedup vs baseline: 2.2962x; 2.2962x over previous
//
#include <hip/hip_runtime.h>
#include <hip/hip_bf16.h>

using f32x4  = __attribute__((ext_vector_type(4))) float;
using bf16x8 = __attribute__((ext_vector_type(8))) short;

__device__ __forceinline__ unsigned short f2bf(float f) {
    union { __hip_bfloat16 h; unsigned short u; } cv;
    cv.h = __float2bfloat16(f);
    return cv.u;
}
__device__ __forceinline__ unsigned int pack2bf(float lo, float hi) {
    float2 t; t.x = lo; t.y = hi;
    union { __hip_bfloat162 h; unsigned int u; } cv;
    cv.h = __float22bfloat162_rn(t);
    return cv.u;
}
__device__ __forceinline__ float bf2f(unsigned short u) {
    return __uint_as_float((unsigned)u << 16);
}

// ---------------- prep: converts / packs (source-coalesced reads) ----------------
__global__ __launch_bounds__(512) void prep_kernel(
        const float* __restrict__ E, const float* __restrict__ Wsc0, const float* __restrict__ Wsc1,
        const float* __restrict__ Wfw, const float* __restrict__ bfw,
        const float* __restrict__ Wbw, const float* __restrict__ bbw,
        const float* __restrict__ Wlin,
        unsigned short* __restrict__ E16, unsigned short* __restrict__ W0p,
        unsigned short* __restrict__ WabP,
        unsigned short* __restrict__ WcatT, unsigned short* __restrict__ WlinT,
        float* __restrict__ bsumS, unsigned short* __restrict__ W1p) {
    const int NE = 131072, NW0 = 131072, NWAB = 262144, NCAT = 524288, NLIN = 131072, NW1P = 8192;
    const int total = NE + NW0 + NWAB + NCAT + NLIN + NW1P + 512;
    for (int idx = blockIdx.x * 512 + threadIdx.x; idx < total; idx += 512 * 512) {
        int t = idx;
        if (t < NE) { E16[t] = f2bf(E[t]); continue; }
        t -= NE;
        if (t < NW0) {
            int k = t >> 9, f = t & 511;
            int w = f >> 6, nb = (f >> 4) & 3, l15 = f & 15;
            int kk = k >> 5, l4 = (k >> 3) & 3, e = k & 7;
            W0p[((((w * 4 + nb) * 8 + kk) * 64) + l4 * 16 + l15) * 8 + e] = f2bf(Wsc0[(512 + k) * 512 + f]);
            continue;
        }
        t -= NW0;
        if (t < NWAB) {
            int r = t >> 9, col = t & 511;
            int k = r & 255;
            int fcol = (r < 256) ? col : (512 + col);
            int wf = fcol >> 6, nb = (fcol >> 4) & 3, l15 = fcol & 15;
            int kk = k >> 5, l4 = (k >> 3) & 3, e = k & 7;
            WabP[((((wf * 4 + nb) * 8 + kk) * 64) + l4 * 16 + l15) * 8 + e] = f2bf(Wsc0[r * 512 + col]);
            continue;
        }
        t -= NWAB;
        if (t < NCAT) {
            int e = t & 127, k = (t >> 7) & 255, r = (t >> 15) & 3, d = (t >> 17) & 1, l = t >> 18;
            const float* src = (d == 0) ? Wfw : Wbw;
            float v = src[((l * 4 + r) * 256 + k) * 128 + e];
            WcatT[(l * 1024 + d * 512 + r * 128 + e) * 256 + k] = f2bf(v);
            continue;
        }
        t -= NCAT;
        if (t < NLIN) {
            int d = t & 255, f = (t >> 8) & 255, l = t >> 16;
            WlinT[(l * 256 + d) * 256 + f] = f2bf(Wlin[(l * 256 + f) * 256 + d]);
            continue;
        }
        t -= NLIN;
        if (t < NW1P) {
            int e = t & 7, lane = (t >> 3) & 63, kap = t >> 9;
            int fp = kap * 32 + (lane >> 4) * 8 + e;
            int w = fp >> 6, q = (fp >> 2) & 15, nb = fp & 3;
            int f = w * 64 + nb * 16 + q;
            int r = lane & 15;
            W1p[t] = (r < 4) ? f2bf(Wsc1[f * 4 + r]) : (unsigned short)0;
            continue;
        }
        t -= NW1P;
        {
            int f = t & 255, l = t >> 8;
            float s = 0.f;
            if (f < 128) { for (int r = 0; r < 4; ++r) s += bbw[(l * 4 + r) * 128 + f]; }
            else         { for (int r = 0; r < 4; ++r) s += bfw[(l * 4 + r) * 128 + (f - 128)]; }
            bsumS[l * 256 + f] = s;
        }
    }
}

// ---------------- uv: U=E@W0a (+b0, nb-paired pack), V=E@W0b (fp32 row-major) via MFMA ----------------
__global__ __launch_bounds__(512) void uv_kernel(const unsigned short* __restrict__ E16,
                                                 const unsigned short* __restrict__ WabP,
                                                 const float* __restrict__ bsc0,
                                                 unsigned short* __restrict__ Upk,
                                                 float* __restrict__ V) {
    __shared__ unsigned short sE[32 * 256];
    const int jt = blockIdx.x;
    const int tid = threadIdx.x, lane = tid & 63, w = tid >> 6;
    const int l15 = lane & 15, l4 = lane >> 4;
#pragma unroll
    for (int it = 0; it < 2; ++it) {
        int u = it * 512 + tid;
        int row = u >> 5, slot = u & 31;
        uint4 v = *(const uint4*)(E16 + (jt * 32 + row) * 256 + slot * 8);
        *(uint4*)((char*)sE + row * 512 + ((slot * 16) ^ ((row & 7) << 4))) = v;
    }
    __syncthreads();
    const bf16x8* Wab8 = (const bf16x8*)WabP;
    f32x4 acc[2][8];
#pragma unroll
    for (int a_ = 0; a_ < 2; ++a_)
#pragma unroll
        for (int b_ = 0; b_ < 8; ++b_) acc[a_][b_] = (f32x4){0.f, 0.f, 0.f, 0.f};
#pragma unroll
    for (int kk = 0; kk < 8; ++kk) {
        bf16x8 af[2];
#pragma unroll
        for (int mbl = 0; mbl < 2; ++mbl) {
            int row = mbl * 16 + l15;
            af[mbl] = *(const bf16x8*)((char*)sE + row * 512 + ((kk * 64 + l4 * 16) ^ ((row & 7) << 4)));
        }
#pragma unroll
        for (int nb = 0; nb < 8; ++nb) {
            int wf = 2 * w + (nb >> 2);
            bf16x8 bfr = Wab8[((wf * 4 + (nb & 3)) * 8 + kk) * 64 + lane];
#pragma unroll
            for (int mbl = 0; mbl < 2; ++mbl)
                acc[mbl][nb] = __builtin_amdgcn_mfma_f32_16x16x32_bf16(af[mbl], bfr, acc[mbl][nb], 0, 0, 0);
        }
    }
#pragma unroll
    for (int mbl = 0; mbl < 2; ++mbl) {
        int j_base = jt * 32 + mbl * 16 + l4 * 4;
#pragma unroll
        for (int nb8 = 0; nb8 < 8; ++nb8) {
            int f_g = (2 * w + (nb8 >> 2)) * 64 + (nb8 & 3) * 16 + l15;
            if (f_g < 512) {
                float b0f = bsc0[f_g];
                ushort4 o;
                o.x = f2bf(acc[mbl][nb8][0] + b0f);
                o.y = f2bf(acc[mbl][nb8][1] + b0f);
                o.z = f2bf(acc[mbl][nb8][2] + b0f);
                o.w = f2bf(acc[mbl][nb8][3] + b0f);
                int jtp = j_base >> 6, mbp = (j_base >> 4) & 3;
                int wp = f_g >> 6, nbp = (f_g >> 4) & 3;
                int lanep = l4 * 16 + l15;
                *(ushort4*)(Upk + ((((jtp * 8 + wp) * 4 + mbp) * 2 + (nbp >> 1)) * 64 + lanep) * 8 + (nbp & 1) * 4) = o;
            } else {
                int fv = f_g - 512;
#pragma unroll
                for (int reg = 0; reg < 4; ++reg)
                    V[(j_base + reg) * 512 + fv] = acc[mbl][nb8][reg];
            }
        }
    }
}

// ---------------- pair scorer: R7 structure + wave-staggered kk + setprio ----------------
__global__ __launch_bounds__(512, 2) void pair_kernel(
    const unsigned short* __restrict__ E16, const unsigned short* __restrict__ W0p,
    const unsigned short* __restrict__ Upk, const float* __restrict__ V,
    const unsigned short* __restrict__ W1p, const float* __restrict__ b1,
    unsigned short* __restrict__ A16) {

    __shared__ unsigned short bufL[2 * 64 * 256];
    __shared__ float vrow[2][512];
    __shared__ float scoresL[2][256];

    const int i0 = blockIdx.x * 2, i1 = i0 + 1;
    const int jt = blockIdx.y;
    const int j0 = jt * 64;
    const int tid = threadIdx.x;
    const int lane = tid & 63;
    const int w = tid >> 6;
    const int l15 = lane & 15, l4 = lane >> 4;

    uint4 uq[4][2];
#pragma unroll
    for (int mb = 0; mb < 4; ++mb)
#pragma unroll
        for (int nbh = 0; nbh < 2; ++nbh)
            uq[mb][nbh] = *(const uint4*)(Upk + ((((jt * 8 + w) * 4 + mb) * 2 + nbh) * 64 + lane) * 8);
    vrow[0][tid] = V[i0 * 512 + tid];
    vrow[1][tid] = V[i1 * 512 + tid];
    if (tid < 256) { scoresL[0][tid] = b1[tid & 3]; scoresL[1][tid] = b1[tid & 3]; }

    // stage both product tiles (conflict-free writes)
    {
        int m = tid >> 3;
        int s = tid & 7;
        const bf16x8* ejp  = (const bf16x8*)(E16 + (j0 + m) * 256 + s * 8);
        const bf16x8* ei0p = (const bf16x8*)(E16 + i0 * 256 + s * 8);
        const bf16x8* ei1p = (const bf16x8*)(E16 + i1 * 256 + s * 8);
        char* base = (char*)bufL;
#pragma unroll
        for (int c = 0; c < 4; ++c) {
            bf16x8 ej = ejp[c * 8], e0 = ei0p[c * 8], e1 = ei1p[c * 8];
            uint4 v0, v1;
            unsigned* p0 = (unsigned*)&v0;
            unsigned* p1 = (unsigned*)&v1;
#pragma unroll
            for (int e2 = 0; e2 < 4; ++e2) {
                float jl = bf2f((unsigned short)ej[e2 * 2]), jh = bf2f((unsigned short)ej[e2 * 2 + 1]);
                p0[e2] = pack2bf(jl * bf2f((unsigned short)e0[e2 * 2]), jh * bf2f((unsigned short)e0[e2 * 2 + 1]));
                p1[e2] = pack2bf(jl * bf2f((unsigned short)e1[e2 * 2]), jh * bf2f((unsigned short)e1[e2 * 2 + 1]));
            }
            int off = m * 512 + ((s * 16 + c * 128) ^ ((m & 7) << 4));
            *(uint4*)(base + off) = v0;
            *(uint4*)(base + 32768 + off) = v1;
        }
    }

    f32x4 acc0[4][4], acc1[4][4];
#pragma unroll
    for (int mb = 0; mb < 4; ++mb)
#pragma unroll
        for (int nbh = 0; nbh < 2; ++nbh) {
            const unsigned short* us = (const unsigned short*)&uq[mb][nbh];
#pragma unroll
            for (int h = 0; h < 2; ++h) {
                int nb = nbh * 2 + h;
                float v0f = vrow[0][w * 64 + nb * 16 + l15];
                float v1f = vrow[1][w * 64 + nb * 16 + l15];
#pragma unroll
                for (int reg = 0; reg < 4; ++reg) {
                    float uu = bf2f(us[h * 4 + reg]);
                    acc0[mb][nb][reg] = uu + v0f;
                    acc1[mb][nb][reg] = uu + v1f;
                }
            }
        }
    __syncthreads();

    // ---- main loop: per-wave staggered kk order breaks lockstep; setprio favors MFMA phase ----
    const char* pbase = (const char*)bufL;
    const bf16x8* Wp8 = (const bf16x8*)W0p;
#pragma unroll
    for (int kx = 0; kx < 8; ++kx) {
        const int kk = (kx + w) & 7;
        bf16x8 bfr[4];
#pragma unroll
        for (int nb = 0; nb < 4; ++nb)
            bfr[nb] = Wp8[((w * 4 + nb) * 8 + kk) * 64 + lane];
        bf16x8 afr[4];
#pragma unroll
        for (int mb = 0; mb < 4; ++mb) {
            int row = mb * 16 + l15;
            afr[mb] = *(const bf16x8*)(pbase + row * 512 + ((kk * 64 + l4 * 16) ^ ((row & 7) << 4)));
        }
        __builtin_amdgcn_s_setprio(1);
#pragma unroll
        for (int mb = 0; mb < 4; ++mb)
#pragma unroll
            for (int nb = 0; nb < 4; ++nb)
                acc0[mb][nb] = __builtin_amdgcn_mfma_f32_16x16x32_bf16(afr[mb], bfr[nb], acc0[mb][nb], 0, 0, 0);
        __builtin_amdgcn_s_setprio(0);
#pragma unroll
        for (int mb = 0; mb < 4; ++mb) {
            int row = mb * 16 + l15;
            afr[mb] = *(const bf16x8*)(pbase + 32768 + row * 512 + ((kk * 64 + l4 * 16) ^ ((row & 7) << 4)));
        }
        __builtin_amdgcn_s_setprio(1);
#pragma unroll
        for (int mb = 0; mb < 4; ++mb)
#pragma unroll
            for (int nb = 0; nb < 4; ++nb)
                acc1[mb][nb] = __builtin_amdgcn_mfma_f32_16x16x32_bf16(afr[mb], bfr[nb], acc1[mb][nb], 0, 0, 0);
        __builtin_amdgcn_s_setprio(0);
    }
    __syncthreads();

    // ---- epilogue per i: H = relu(acc), S = H @ W1p ----
    char* hb = (char*)bufL;
    const bf16x8* W1p8 = (const bf16x8*)W1p;
    bf16x8 w1f[2];
#pragma unroll
    for (int kl = 0; kl < 2; ++kl) w1f[kl] = W1p8[(w * 2 + kl) * 64 + lane];

#pragma unroll
    for (int ii = 0; ii < 2; ++ii) {
#pragma unroll
        for (int mb = 0; mb < 4; ++mb)
#pragma unroll
            for (int reg = 0; reg < 4; ++reg) {
                int rl = mb * 16 + l4 * 4 + reg;
                f32x4* A = (ii == 0) ? &acc0[mb][0] : &acc1[mb][0];
                float h0 = fmaxf(A[0][reg], 0.f);
                float h1 = fmaxf(A[1][reg], 0.f);
                float h2 = fmaxf(A[2][reg], 0.f);
                float h3 = fmaxf(A[3][reg], 0.f);
                uint2 val;
                val.x = pack2bf(h0, h1);
                val.y = pack2bf(h2, h3);
                *(uint2*)(hb + rl * 1024 + ((w * 128 + l15 * 8) ^ ((rl & 7) << 4))) = val;
            }
        __syncthreads();
        f32x4 accS[4];
#pragma unroll
        for (int mb = 0; mb < 4; ++mb) {
            accS[mb] = (f32x4){0.f, 0.f, 0.f, 0.f};
            int rl = mb * 16 + l15;
#pragma unroll
            for (int kl = 0; kl < 2; ++kl) {
                bf16x8 ha = *(const bf16x8*)(hb + rl * 1024 + (((w * 2 + kl) * 64 + l4 * 16) ^ ((rl & 7) << 4)));
                accS[mb] = __builtin_amdgcn_mfma_f32_16x16x32_bf16(ha, w1f[kl], accS[mb], 0, 0, 0);
            }
        }
        if (l15 < 4) {
#pragma unroll
            for (int mb = 0; mb < 4; ++mb)
#pragma unroll
                for (int reg = 0; reg < 4; ++reg)
                    atomicAdd(&scoresL[ii][(mb * 16 + l4 * 4 + reg) * 4 + l15], accS[mb][reg]);
        }
        __syncthreads();
    }

    if (tid < 128) {
        int ii = tid >> 6, m = tid & 63;
        int j = j0 + m, ic = i0 + ii;
        float s0 = scoresL[ii][m * 4 + 0], s1 = scoresL[ii][m * 4 + 1];
        float sA = scoresL[ii][m * 4 + 2], sB = scoresL[ii][m * 4 + 3];
        float mx = fmaxf(fmaxf(s0, s1), fmaxf(sA, sB));
        float e0 = __expf(s0 - mx), e1 = __expf(s1 - mx), e2 = __expf(sA - mx), e3 = __expf(sB - mx);
        float inv = 1.f / (e0 + e1 + e2 + e3);
        float p_[4] = {e0 * inv, e1 * inv, e2 * inv, e3 * inv};
        if (j == ic) { p_[0] = p_[1] = p_[2] = p_[3] = 0.f; }
#pragma unroll
        for (int r = 0; r < 4; ++r)
            A16[(r * 512 + ic) * 512 + j] = f2bf(p_[r]);
    }
}

// ---------------- LDS panel helpers ----------------
template<int K>
__device__ __forceinline__ void stageP(unsigned short* lds, const unsigned short* g, int ldg, int tid) {
    constexpr int SLOTS = K / 8;
#pragma unroll
    for (int it = 0; it < (32 * SLOTS) / 256; ++it) {
        int u = it * 256 + tid;
        int row = u / SLOTS, slot = u % SLOTS;
        uint4 v = *(const uint4*)(g + row * ldg + slot * 8);
        *(uint4*)((char*)lds + row * (K * 2) + ((slot * 16) ^ ((row & 7) << 4))) = v;
    }
}
__device__ __forceinline__ void stage64(unsigned short* lds, const unsigned short* g, int ldg, int tid) {
#pragma unroll
    for (int it = 0; it < 8; ++it) {
        int u = it * 256 + tid;
        int row = u >> 5, slot = u & 31;
        uint4 v = *(const uint4*)(g + row * ldg + slot * 8);
        *(uint4*)((char*)lds + row * 512 + ((slot * 16) ^ ((row & 7) << 4))) = v;
    }
}
template<int K>
__device__ __forceinline__ bf16x8 fragP(const unsigned short* lds, int row, int kc, int l4) {
    return *(const bf16x8*)((const char*)lds + row * (K * 2) + ((((kc * 4 + l4) * 16) ^ ((row & 7) << 4))));
}

// ---------------- c1 ----------------
__global__ __launch_bounds__(256) void c1_kernel(const unsigned short* __restrict__ WcatT,
                                                 const unsigned short* __restrict__ x16,
                                                 unsigned short* __restrict__ supT,
                                                 const unsigned short* __restrict__ A16,
                                                 unsigned short* __restrict__ AT16, int l) {
    __shared__ unsigned short lA[32 * 256], lB[32 * 256];
    int tid = threadIdx.x;
    if (blockIdx.y >= 16) {
        auto t = (unsigned short(*)[65])lA;
        int job = (blockIdx.y - 16) * 32 + blockIdx.x;
        int r = job >> 6, ty = (job >> 3) & 7, tx = job & 7;
        const unsigned short* src = A16 + (r * 512 + ty * 64) * 512 + tx * 64;
        unsigned short* dst = AT16 + (r * 512 + tx * 64) * 512 + ty * 64;
#pragma unroll
        for (int it = 0; it < 2; ++it) {
            int u = it * 256 + tid, row = u >> 3, c8 = (u & 7) * 8;
            uint4 v = *(const uint4*)(src + row * 512 + c8);
            const unsigned short* p = (const unsigned short*)&v;
#pragma unroll
            for (int e = 0; e < 8; ++e) t[c8 + e][row] = p[e];
        }
        __syncthreads();
#pragma unroll
        for (int it = 0; it < 2; ++it) {
            int u = it * 256 + tid, row = u >> 3, c8 = (u & 7) * 8;
            uint4 v; unsigned short* p = (unsigned short*)&v;
#pragma unroll
            for (int e = 0; e < 8; ++e) p[e] = t[row][c8 + e];
            *(uint4*)(dst + row * 512 + c8) = v;
        }
        return;
    }
    int c0 = blockIdx.x * 32, jt0 = blockIdx.y * 32;
    int lane = tid & 63, w = tid >> 6;
    int wr = (w >> 1) * 16, wc = (w & 1) * 16;
    int l15 = lane & 15, l4 = lane >> 4;
    stageP<256>(lA, WcatT + l * 262144 + c0 * 256, 256, tid);
    stageP<256>(lB, x16 + jt0 * 256, 256, tid);
    __syncthreads();
    f32x4 a0 = {0.f,0.f,0.f,0.f}, a1 = {0.f,0.f,0.f,0.f};
#pragma unroll
    for (int kc = 0; kc < 8; kc += 2) {
        a0 = __builtin_amdgcn_mfma_f32_16x16x32_bf16(fragP<256>(lA, wr + l15, kc, l4),
                                                     fragP<256>(lB, wc + l15, kc, l4), a0, 0, 0, 0);
        a1 = __builtin_amdgcn_mfma_f32_16x16x32_bf16(fragP<256>(lA, wr + l15, kc + 1, l4),
                                                     fragP<256>(lB, wc + l15, kc + 1, l4), a1, 0, 0, 0);
    }
    f32x4 acc = a0 + a1;
#pragma unroll
    for (int reg = 0; reg < 4; ++reg) {
        int c = c0 + wr + l4 * 4 + reg;
        int j = jt0 + wc + l15;
        supT[c * 512 + j] = f2bf(acc[reg]);
    }
}

// ---------------- c2 (split-k) ----------------
__global__ __launch_bounds__(256) void c2_kernel(const unsigned short* __restrict__ A16,
                                                 const unsigned short* __restrict__ AT16,
                                                 const unsigned short* __restrict__ supT,
                                                 float* __restrict__ Pc2) {
    __shared__ unsigned short lA[64 * 256], lB[64 * 256];
    int i0 = blockIdx.x * 64, f0 = blockIdx.y * 64;
    int s = blockIdx.z, r = s >> 1, kh = s & 1;
    bool bw = (f0 < 128);
    int e0 = bw ? f0 : (f0 - 128);
    const unsigned short* Am = bw ? AT16 : A16;
    int tid = threadIdx.x, lane = tid & 63, w = tid >> 6;
    int wr = (w >> 1) * 32, wc = (w & 1) * 32;
    int l15 = lane & 15, l4 = lane >> 4;
    stage64(lA, Am + (r * 512 + i0) * 512 + kh * 256, 512, tid);
    stage64(lB, supT + ((bw ? 512 : 0) + r * 128 + e0) * 512 + kh * 256, 512, tid);
    __syncthreads();
    f32x4 acc[2][2];
#pragma unroll
    for (int a_ = 0; a_ < 2; ++a_)
#pragma unroll
        for (int b_ = 0; b_ < 2; ++b_) acc[a_][b_] = (f32x4){0.f, 0.f, 0.f, 0.f};
#pragma unroll
    for (int kc = 0; kc < 8; ++kc) {
        bf16x8 af[2], bf_[2];
#pragma unroll
        for (int mb = 0; mb < 2; ++mb) af[mb] = fragP<256>(lA, wr + mb * 16 + l15, kc, l4);
#pragma unroll
        for (int nb = 0; nb < 2; ++nb) bf_[nb] = fragP<256>(lB, wc + nb * 16 + l15, kc, l4);
#pragma unroll
        for (int mb = 0; mb < 2; ++mb)
#pragma unroll
            for (int nb = 0; nb < 2; ++nb)
                acc[mb][nb] = __builtin_amdgcn_mfma_f32_16x16x32_bf16(af[mb], bf_[nb], acc[mb][nb], 0, 0, 0);
    }
    float* dst = Pc2 + s * 131072;
#pragma unroll
    for (int mb = 0; mb < 2; ++mb)
#pragma unroll
        for (int nb = 0; nb < 2; ++nb)
#pragma unroll
            for (int reg = 0; reg < 4; ++reg)
                dst[(i0 + wr + mb * 16 + l4 * 4 + reg) * 256 + f0 + wc + nb * 16 + l15] = acc[mb][nb][reg];
}

// ---------------- c3 ----------------
__global__ __launch_bounds__(256) void c3_kernel(const float* __restrict__ Pc2,
                                                 const float* __restrict__ bsumS,
                                                 const unsigned short* __restrict__ WlinT,
                                                 const float* __restrict__ blin,
                                                 const float* __restrict__ xold,
                                                 float* __restrict__ xnew,
                                                 unsigned short* __restrict__ x16out, int l) {
    __shared__ unsigned short lA[32 * 256], lB[32 * 256];
    int i0 = blockIdx.x * 32, d0 = blockIdx.y * 32;
    int tid = threadIdx.x, lane = tid & 63, w = tid >> 6;
    int wr = (w >> 1) * 16, wc = (w & 1) * 16;
    int l15 = lane & 15, l4 = lane >> 4;
#pragma unroll
    for (int g = 0; g < 4; ++g) {
        int u = g * 256 + tid;
        int row = u >> 5, k8 = (u & 31) * 8;
        float s[8] = {0,0,0,0,0,0,0,0};
#pragma unroll
        for (int s8 = 0; s8 < 8; ++s8) {
            const float4* p = (const float4*)(Pc2 + s8 * 131072 + (i0 + row) * 256 + k8);
            float4 a = p[0], b = p[1];
            s[0] += a.x; s[1] += a.y; s[2] += a.z; s[3] += a.w;
            s[4] += b.x; s[5] += b.y; s[6] += b.z; s[7] += b.w;
        }
        uint4 v;
        unsigned* vp = (unsigned*)&v;
#pragma unroll
        for (int e2 = 0; e2 < 4; ++e2) {
            float lo = fmaxf(s[e2 * 2] + bsumS[l * 256 + k8 + e2 * 2], 0.f);
            float hi = fmaxf(s[e2 * 2 + 1] + bsumS[l * 256 + k8 + e2 * 2 + 1], 0.f);
            vp[e2] = pack2bf(lo, hi);
        }
        *(uint4*)((char*)lA + row * 512 + ((k8 * 2) ^ ((row & 7) << 4))) = v;
    }
    stageP<256>(lB, WlinT + l * 65536 + d0 * 256, 256, tid);
    __syncthreads();
    f32x4 a0 = {0.f,0.f,0.f,0.f}, a1 = {0.f,0.f,0.f,0.f};
#pragma unroll
    for (int kc = 0; kc < 8; kc += 2) {
        a0 = __builtin_amdgcn_mfma_f32_16x16x32_bf16(fragP<256>(lA, wr + l15, kc, l4),
                                                     fragP<256>(lB, wc + l15, kc, l4), a0, 0, 0, 0);
        a1 = __builtin_amdgcn_mfma_f32_16x16x32_bf16(fragP<256>(lA, wr + l15, kc + 1, l4),
                                                     fragP<256>(lB, wc + l15, kc + 1, l4), a1, 0, 0, 0);
    }
    f32x4 acc = a0 + a1;
#pragma unroll
    for (int reg = 0; reg < 4; ++reg) {
        int ii = i0 + wr + l4 * 4 + reg;
        int dd = d0 + wc + l15;
        float vv = acc[reg] + blin[l * 256 + dd] + xold[ii * 256 + dd];
        xnew[ii * 256 + dd] = vv;
        x16out[ii * 256 + dd] = f2bf(vv);
    }
}

extern "C" void kernel_launch(void* const* d_in, const int* in_sizes, int n_in,
                              void* d_out, int out_size, void* d_ws, size_t ws_size,
                              hipStream_t stream) {
    const float* E    = (const float*)d_in[0];
    const float* Wsc0 = (const float*)d_in[1];
    const float* bsc0 = (const float*)d_in[2];
    const float* Wsc1 = (const float*)d_in[3];
    const float* bsc1 = (const float*)d_in[4];
    const float* Wfw  = (const float*)d_in[5];
    const float* bfw  = (const float*)d_in[6];
    const float* Wbw  = (const float*)d_in[7];
    const float* bbw  = (const float*)d_in[8];
    const float* Wlin = (const float*)d_in[9];
    const float* blin = (const float*)d_in[10];
    float* out = (float*)d_out;

    char* ws = (char*)d_ws;
    size_t off = 0;
    unsigned short* E16   = (unsigned short*)(ws + off); off += 512 * 256 * 2;
    unsigned short* W0p   = (unsigned short*)(ws + off); off += 512 * 256 * 2;
    unsigned short* WabP  = (unsigned short*)(ws + off); off += 1024 * 256 * 2;
    unsigned short* WcatT = (unsigned short*)(ws + off); off += 2 * 1024 * 256 * 2;
    unsigned short* WlinT = (unsigned short*)(ws + off); off += 2 * 256 * 256 * 2;
    float* bsumS          = (float*)(ws + off);          off += 2 * 256 * 4;
    unsigned short* Upk   = (unsigned short*)(ws + off); off += 512 * 512 * 2;
    float* V              = (float*)(ws + off);          off += 512 * 512 * 4;
    unsigned short* W1p   = (unsigned short*)(ws + off); off += 16 * 64 * 8 * 2;
    unsigned short* A16   = (unsigned short*)(ws + off); off += 4 * 512 * 512 * 2;
    unsigned short* AT16  = (unsigned short*)(ws + off); off += 4 * 512 * 512 * 2;
    unsigned short* supT  = (unsigned short*)(ws + off); off += 1024 * 512 * 2;
    float* Pc2            = (float*)(ws + off);          off += 8 * 512 * 256 * 4;
    float* xf1            = (float*)(ws + off);          off += 512 * 256 * 4;
    unsigned short* x16_1 = (unsigned short*)(ws + off); off += 512 * 256 * 2;

    prep_kernel<<<512, 512, 0, stream>>>(E, Wsc0, Wsc1, Wfw, bfw, Wbw, bbw, Wlin,
                                         E16, W0p, WabP, WcatT, WlinT, bsumS, W1p);
    uv_kernel<<<16, 512, 0, stream>>>(E16, WabP, bsc0, Upk, V);
    pair_kernel<<<dim3(256, 8), 512, 0, stream>>>(E16, W0p, Upk, V, W1p, bsc1, A16);

    for (int l = 0; l < 2; ++l) {
        const unsigned short* xin16 = (l == 0) ? E16 : x16_1;
        const float* xoldf = (l == 0) ? E : xf1;
        float* xout = (l == 0) ? xf1 : out;
        c1_kernel<<<dim3(32, (l == 0) ? 24 : 16), 256, 0, stream>>>(WcatT, xin16, supT, A16, AT16, l);
        c2_kernel<<<dim3(8, 4, 8), 256, 0, stream>>>(A16, AT16, supT, Pc2);
        c3_kernel<<<dim3(16, 8), 256, 0, stream>>>(Pc2, bsumS, WlinT, blin, xoldf, xout, x16_1, l);
    }
    (void)in_sizes; (void)n_in; (void)out_size; (void)ws_size;
}

// Round 13
// 188.242 us; speedup vs baseline: 2.3376x; 1.0181x over previous
//
#include <hip/hip_runtime.h>
#include <hip/hip_bf16.h>

using f32x4   = __attribute__((ext_vector_type(4))) float;
using f32x16  = __attribute__((ext_vector_type(16))) float;
using bf16x8  = __attribute__((ext_vector_type(8))) short;

__device__ __forceinline__ unsigned short f2bf(float f) {
    union { __hip_bfloat16 h; unsigned short u; } cv;
    cv.h = __float2bfloat16(f);
    return cv.u;
}
__device__ __forceinline__ unsigned int pack2bf(float lo, float hi) {
    float2 t; t.x = lo; t.y = hi;
    union { __hip_bfloat162 h; unsigned int u; } cv;
    cv.h = __float22bfloat162_rn(t);
    return cv.u;
}
__device__ __forceinline__ float bf2f(unsigned short u) {
    return __uint_as_float((unsigned)u << 16);
}

// ---------------- prep ----------------
// W0pA: A-frag pack for 32x32x16 (W0c as A, rows=f): value W0c[k][f]:
//   fblk=f>>5, kk=k>>4, lane=((k>>3)&1)*32+(f&31), e=k&7 -> [((fblk*16+kk)*64+lane)*8+e]
// W1A : A-frag for S-MFMA: row=r=lane&31 (<4 else 0), k-chunk kc: f=fblk*32+kc*16+(lane>>5)*8+e
// Upk32: C-layout pack of U+b0: (j,f): jblk=j>>5, fblk=f>>5, lane=((f>>2)&1)*32+(j&31),
//   reg=(f&3)|(((f>>3)&3)<<2) -> [((jblk*16+fblk)*64+lane)*16+reg]
__global__ __launch_bounds__(512) void prep_kernel(
        const float* __restrict__ E, const float* __restrict__ Wsc0, const float* __restrict__ Wsc1,
        const float* __restrict__ Wfw, const float* __restrict__ bfw,
        const float* __restrict__ Wbw, const float* __restrict__ bbw,
        const float* __restrict__ Wlin,
        unsigned short* __restrict__ E16, unsigned short* __restrict__ W0pA,
        unsigned short* __restrict__ WabP,
        unsigned short* __restrict__ WcatT, unsigned short* __restrict__ WlinT,
        float* __restrict__ bsumS, unsigned short* __restrict__ W1A) {
    const int NE = 131072, NW0 = 131072, NWAB = 262144, NCAT = 524288, NLIN = 131072, NW1A = 16384;
    const int total = NE + NW0 + NWAB + NCAT + NLIN + NW1A + 512;
    for (int idx = blockIdx.x * 512 + threadIdx.x; idx < total; idx += 512 * 512) {
        int t = idx;
        if (t < NE) { E16[t] = f2bf(E[t]); continue; }
        t -= NE;
        if (t < NW0) {
            int k = t >> 9, f = t & 511;
            int fblk = f >> 5, kk = k >> 4, lh = (k >> 3) & 1, e = k & 7;
            int lane = lh * 32 + (f & 31);
            W0pA[((fblk * 16 + kk) * 64 + lane) * 8 + e] = f2bf(Wsc0[(512 + k) * 512 + f]);
            continue;
        }
        t -= NW0;
        if (t < NWAB) {
            int r = t >> 9, col = t & 511;
            int k = r & 255;
            int fcol = (r < 256) ? col : (512 + col);
            int wf = fcol >> 6, nb = (fcol >> 4) & 3, l15 = fcol & 15;
            int kk = k >> 5, l4 = (k >> 3) & 3, e = k & 7;
            WabP[((((wf * 4 + nb) * 8 + kk) * 64) + l4 * 16 + l15) * 8 + e] = f2bf(Wsc0[r * 512 + col]);
            continue;
        }
        t -= NWAB;
        if (t < NCAT) {
            int e = t & 127, k = (t >> 7) & 255, r = (t >> 15) & 3, d = (t >> 17) & 1, l = t >> 18;
            const float* src = (d == 0) ? Wfw : Wbw;
            float v = src[((l * 4 + r) * 256 + k) * 128 + e];
            WcatT[(l * 1024 + d * 512 + r * 128 + e) * 256 + k] = f2bf(v);
            continue;
        }
        t -= NCAT;
        if (t < NLIN) {
            int d = t & 255, f = (t >> 8) & 255, l = t >> 16;
            WlinT[(l * 256 + d) * 256 + f] = f2bf(Wlin[(l * 256 + f) * 256 + d]);
            continue;
        }
        t -= NLIN;
        if (t < NW1A) {
            int e = t & 7, lane = (t >> 3) & 63, kc = (t >> 9) & 1, fblk = t >> 10;
            int f = fblk * 32 + kc * 16 + (lane >> 5) * 8 + e;
            int r = lane & 31;
            W1A[t] = (r < 4) ? f2bf(Wsc1[f * 4 + r]) : (unsigned short)0;
            continue;
        }
        t -= NW1A;
        {
            int f = t & 255, l = t >> 8;
            float s = 0.f;
            if (f < 128) { for (int r = 0; r < 4; ++r) s += bbw[(l * 4 + r) * 128 + f]; }
            else         { for (int r = 0; r < 4; ++r) s += bfw[(l * 4 + r) * 128 + (f - 128)]; }
            bsumS[l * 256 + f] = s;
        }
    }
}

// ---------------- uv: U=E@W0a (+b0 -> Upk32 32x32-C pack), V=E@W0b (fp32 row-major) ----------------
__global__ __launch_bounds__(512) void uv_kernel(const unsigned short* __restrict__ E16,
                                                 const unsigned short* __restrict__ WabP,
                                                 const float* __restrict__ bsc0,
                                                 unsigned short* __restrict__ Upk32,
                                                 float* __restrict__ V) {
    __shared__ unsigned short sE[32 * 256];
    const int jt = blockIdx.x;
    const int tid = threadIdx.x, lane = tid & 63, w = tid >> 6;
    const int l15 = lane & 15, l4 = lane >> 4;
#pragma unroll
    for (int it = 0; it < 2; ++it) {
        int u = it * 512 + tid;
        int row = u >> 5, slot = u & 31;
        uint4 v = *(const uint4*)(E16 + (jt * 32 + row) * 256 + slot * 8);
        *(uint4*)((char*)sE + row * 512 + ((slot * 16) ^ ((row & 7) << 4))) = v;
    }
    __syncthreads();
    const bf16x8* Wab8 = (const bf16x8*)WabP;
    f32x4 acc[2][8];
#pragma unroll
    for (int a_ = 0; a_ < 2; ++a_)
#pragma unroll
        for (int b_ = 0; b_ < 8; ++b_) acc[a_][b_] = (f32x4){0.f, 0.f, 0.f, 0.f};
#pragma unroll
    for (int kk = 0; kk < 8; ++kk) {
        bf16x8 af[2];
#pragma unroll
        for (int mbl = 0; mbl < 2; ++mbl) {
            int row = mbl * 16 + l15;
            af[mbl] = *(const bf16x8*)((char*)sE + row * 512 + ((kk * 64 + l4 * 16) ^ ((row & 7) << 4)));
        }
#pragma unroll
        for (int nb = 0; nb < 8; ++nb) {
            int wf = 2 * w + (nb >> 2);
            bf16x8 bfr = Wab8[((wf * 4 + (nb & 3)) * 8 + kk) * 64 + lane];
#pragma unroll
            for (int mbl = 0; mbl < 2; ++mbl)
                acc[mbl][nb] = __builtin_amdgcn_mfma_f32_16x16x32_bf16(af[mbl], bfr, acc[mbl][nb], 0, 0, 0);
        }
    }
#pragma unroll
    for (int mbl = 0; mbl < 2; ++mbl) {
        int j_base = jt * 32 + mbl * 16 + l4 * 4;
#pragma unroll
        for (int nb8 = 0; nb8 < 8; ++nb8) {
            int f_g = (2 * w + (nb8 >> 2)) * 64 + (nb8 & 3) * 16 + l15;
            if (f_g < 512) {
                float b0f = bsc0[f_g];
                int fblk = f_g >> 5;
                int lane2 = ((f_g >> 2) & 1) * 32;
                int reg2 = (f_g & 3) | (((f_g >> 3) & 3) << 2);
#pragma unroll
                for (int reg = 0; reg < 4; ++reg) {
                    int j = j_base + reg;
                    Upk32[(((j >> 5) * 16 + fblk) * 64 + lane2 + (j & 31)) * 16 + reg2] =
                        f2bf(acc[mbl][nb8][reg] + b0f);
                }
            } else {
                int fv = f_g - 512;
#pragma unroll
                for (int reg = 0; reg < 4; ++reg)
                    V[(j_base + reg) * 512 + fv] = acc[mbl][nb8][reg];
            }
        }
    }
}

// ---------------- pair scorer: 32x32 MFMA, swapped operands, fc in-block loop ----------------
__global__ __launch_bounds__(512) void pair_kernel(
    const unsigned short* __restrict__ E16, const unsigned short* __restrict__ W0pA,
    const unsigned short* __restrict__ Upk32, const float* __restrict__ V,
    const unsigned short* __restrict__ W1A, const float* __restrict__ b1,
    unsigned short* __restrict__ A16) {

    __shared__ unsigned short prodL[2 * 64 * 256];   // 64 KB
    __shared__ float vrow[2][512];                   // 4 KB
    __shared__ float scoresL[2][256];                // 2 KB

    const int i0 = blockIdx.x * 2, i1 = i0 + 1;
    const int jt = blockIdx.y;
    const int j0 = jt * 64;
    const int tid = threadIdx.x;
    const int lane = tid & 63;
    const int w = tid >> 6;
    const int jh = w >> 2, fg = w & 3;
    const int l31 = lane & 31, lh = lane >> 5;

    vrow[0][tid] = V[i0 * 512 + tid];
    vrow[1][tid] = V[i1 * 512 + tid];
    if (tid < 256) { scoresL[0][tid] = b1[tid & 3]; scoresL[1][tid] = b1[tid & 3]; }

    // stage both product tiles (64 j x 256 k), conflict-free
    {
        int m = tid >> 3;
        int s = tid & 7;
        const bf16x8* ejp  = (const bf16x8*)(E16 + (j0 + m) * 256 + s * 8);
        const bf16x8* ei0p = (const bf16x8*)(E16 + i0 * 256 + s * 8);
        const bf16x8* ei1p = (const bf16x8*)(E16 + i1 * 256 + s * 8);
        char* base = (char*)prodL;
#pragma unroll
        for (int c = 0; c < 4; ++c) {
            bf16x8 ej = ejp[c * 8], e0 = ei0p[c * 8], e1 = ei1p[c * 8];
            uint4 v0, v1;
            unsigned* p0 = (unsigned*)&v0;
            unsigned* p1 = (unsigned*)&v1;
#pragma unroll
            for (int e2 = 0; e2 < 4; ++e2) {
                float jl = bf2f((unsigned short)ej[e2 * 2]), jhv = bf2f((unsigned short)ej[e2 * 2 + 1]);
                p0[e2] = pack2bf(jl * bf2f((unsigned short)e0[e2 * 2]), jhv * bf2f((unsigned short)e0[e2 * 2 + 1]));
                p1[e2] = pack2bf(jl * bf2f((unsigned short)e1[e2 * 2]), jhv * bf2f((unsigned short)e1[e2 * 2 + 1]));
            }
            int off = m * 512 + ((s * 16 + c * 128) ^ ((m & 7) << 4));
            *(uint4*)(base + off) = v0;
            *(uint4*)(base + 32768 + off) = v1;
        }
    }
    __syncthreads();

    const char* pbase = (const char*)prodL;
    const bf16x8* wA = (const bf16x8*)W0pA;
    const bf16x8* w1A8 = (const bf16x8*)W1A;
    const int row = jh * 32 + l31;
    const int rowoff = row * 512;
    const int swz = (row & 7) << 4;

    f32x16 accS[2];
    accS[0] = (f32x16)(0.f);
    accS[1] = (f32x16)(0.f);

#pragma unroll
    for (int fc = 0; fc < 2; ++fc) {
        // ---- acc init: U(+b0) + V ----
        f32x16 acc[2][2];
#pragma unroll
        for (int nb = 0; nb < 2; ++nb) {
            int fblk = fc * 8 + fg * 2 + nb;
            const uint4* up = (const uint4*)(Upk32 + (((jt * 2 + jh) * 16 + fblk) * 64 + lane) * 16);
            uint4 ua = up[0], ub = up[1];
            const unsigned short* us = (const unsigned short*)&ua;
            const unsigned short* vs = (const unsigned short*)&ub;
#pragma unroll
            for (int reg = 0; reg < 16; ++reg) {
                int frow = (reg & 3) + 8 * (reg >> 2) + 4 * lh;
                int f = fc * 256 + fg * 64 + nb * 32 + frow;
                float uu = bf2f(reg < 8 ? us[reg] : vs[reg - 8]);
                acc[0][nb][reg] = uu + vrow[0][f];
                acc[1][nb][reg] = uu + vrow[1][f];
            }
        }
        // ---- K loop: 16 steps of K=16 ----
#pragma unroll
        for (int kk = 0; kk < 16; ++kk) {
            bf16x8 af[2];
#pragma unroll
            for (int nb = 0; nb < 2; ++nb)
                af[nb] = wA[((fc * 8 + fg * 2 + nb) * 16 + kk) * 64 + lane];
            int off = rowoff + ((kk * 32 + lh * 16) ^ swz);
            bf16x8 bf0 = *(const bf16x8*)(pbase + off);
            bf16x8 bf1 = *(const bf16x8*)(pbase + 32768 + off);
#pragma unroll
            for (int nb = 0; nb < 2; ++nb) {
                acc[0][nb] = __builtin_amdgcn_mfma_f32_32x32x16_bf16(af[nb], bf0, acc[0][nb], 0, 0, 0);
                acc[1][nb] = __builtin_amdgcn_mfma_f32_32x32x16_bf16(af[nb], bf1, acc[1][nb], 0, 0, 0);
            }
        }
        // ---- fold into accS: S += W1A x relu(acc) ----
#pragma unroll
        for (int i = 0; i < 2; ++i) {
#pragma unroll
            for (int nb = 0; nb < 2; ++nb) {
                int fblk = fc * 8 + fg * 2 + nb;
                float hv[16];
#pragma unroll
                for (int reg = 0; reg < 16; ++reg) hv[reg] = fmaxf(acc[i][nb][reg], 0.f);
#pragma unroll
                for (int kc = 0; kc < 2; ++kc) {
                    unsigned pe0 = pack2bf(hv[((2 * kc) & 3) * 4 + 0], hv[((2 * kc) & 3) * 4 + 1]);
                    unsigned pe1 = pack2bf(hv[((2 * kc) & 3) * 4 + 2], hv[((2 * kc) & 3) * 4 + 3]);
                    unsigned po0 = pack2bf(hv[((2 * kc + 1) & 3) * 4 + 0], hv[((2 * kc + 1) & 3) * 4 + 1]);
                    unsigned po1 = pack2bf(hv[((2 * kc + 1) & 3) * 4 + 2], hv[((2 * kc + 1) & 3) * 4 + 3]);
                    unsigned k0 = lh ? po0 : pe0, k1 = lh ? po1 : pe1;
                    unsigned s0 = lh ? pe0 : po0, s1 = lh ? pe1 : po1;
                    unsigned r0 = (unsigned)__shfl_xor((int)s0, 32);
                    unsigned r1 = (unsigned)__shfl_xor((int)s1, 32);
                    union { bf16x8 v; unsigned u[4]; } bb;
                    bb.u[0] = lh ? r0 : k0;
                    bb.u[1] = lh ? r1 : k1;
                    bb.u[2] = lh ? k0 : r0;
                    bb.u[3] = lh ? k1 : r1;
                    bf16x8 wf = w1A8[(fblk * 2 + kc) * 64 + lane];
                    accS[i] = __builtin_amdgcn_mfma_f32_32x32x16_bf16(wf, bb.v, accS[i], 0, 0, 0);
                }
            }
        }
    }

    // ---- extract S (rows 0-3 live on lh==0, regs 0-3) ----
    if (lh == 0) {
#pragma unroll
        for (int i = 0; i < 2; ++i)
#pragma unroll
            for (int reg = 0; reg < 4; ++reg)
                atomicAdd(&scoresL[i][(jh * 32 + l31) * 4 + reg], accS[i][reg]);
    }
    __syncthreads();

    if (tid < 128) {
        int ii = tid >> 6, m = tid & 63;
        int j = j0 + m, ic = i0 + ii;
        float s0 = scoresL[ii][m * 4 + 0], s1 = scoresL[ii][m * 4 + 1];
        float sA = scoresL[ii][m * 4 + 2], sB = scoresL[ii][m * 4 + 3];
        float mx = fmaxf(fmaxf(s0, s1), fmaxf(sA, sB));
        float e0 = __expf(s0 - mx), e1 = __expf(s1 - mx), e2 = __expf(sA - mx), e3 = __expf(sB - mx);
        float inv = 1.f / (e0 + e1 + e2 + e3);
        float p_[4] = {e0 * inv, e1 * inv, e2 * inv, e3 * inv};
        if (j == ic) { p_[0] = p_[1] = p_[2] = p_[3] = 0.f; }
#pragma unroll
        for (int r = 0; r < 4; ++r)
            A16[(r * 512 + ic) * 512 + j] = f2bf(p_[r]);
    }
}

// ---------------- LDS panel helpers ----------------
template<int K>
__device__ __forceinline__ void stageP(unsigned short* lds, const unsigned short* g, int ldg, int tid) {
    constexpr int SLOTS = K / 8;
#pragma unroll
    for (int it = 0; it < (32 * SLOTS) / 256; ++it) {
        int u = it * 256 + tid;
        int row = u / SLOTS, slot = u % SLOTS;
        uint4 v = *(const uint4*)(g + row * ldg + slot * 8);
        *(uint4*)((char*)lds + row * (K * 2) + ((slot * 16) ^ ((row & 7) << 4))) = v;
    }
}
__device__ __forceinline__ void stage64(unsigned short* lds, const unsigned short* g, int ldg, int tid) {
#pragma unroll
    for (int it = 0; it < 8; ++it) {
        int u = it * 256 + tid;
        int row = u >> 5, slot = u & 31;
        uint4 v = *(const uint4*)(g + row * ldg + slot * 8);
        *(uint4*)((char*)lds + row * 512 + ((slot * 16) ^ ((row & 7) << 4))) = v;
    }
}
template<int K>
__device__ __forceinline__ bf16x8 fragP(const unsigned short* lds, int row, int kc, int l4) {
    return *(const bf16x8*)((const char*)lds + row * (K * 2) + ((((kc * 4 + l4) * 16) ^ ((row & 7) << 4))));
}

// ---------------- c1 ----------------
__global__ __launch_bounds__(256) void c1_kernel(const unsigned short* __restrict__ WcatT,
                                                 const unsigned short* __restrict__ x16,
                                                 unsigned short* __restrict__ supT,
                                                 const unsigned short* __restrict__ A16,
                                                 unsigned short* __restrict__ AT16, int l) {
    __shared__ unsigned short lA[32 * 256], lB[32 * 256];
    int tid = threadIdx.x;
    if (blockIdx.y >= 16) {
        auto t = (unsigned short(*)[65])lA;
        int job = (blockIdx.y - 16) * 32 + blockIdx.x;
        int r = job >> 6, ty = (job >> 3) & 7, tx = job & 7;
        const unsigned short* src = A16 + (r * 512 + ty * 64) * 512 + tx * 64;
        unsigned short* dst = AT16 + (r * 512 + tx * 64) * 512 + ty * 64;
#pragma unroll
        for (int it = 0; it < 2; ++it) {
            int u = it * 256 + tid, row = u >> 3, c8 = (u & 7) * 8;
            uint4 v = *(const uint4*)(src + row * 512 + c8);
            const unsigned short* p = (const unsigned short*)&v;
#pragma unroll
            for (int e = 0; e < 8; ++e) t[c8 + e][row] = p[e];
        }
        __syncthreads();
#pragma unroll
        for (int it = 0; it < 2; ++it) {
            int u = it * 256 + tid, row = u >> 3, c8 = (u & 7) * 8;
            uint4 v; unsigned short* p = (unsigned short*)&v;
#pragma unroll
            for (int e = 0; e < 8; ++e) p[e] = t[row][c8 + e];
            *(uint4*)(dst + row * 512 + c8) = v;
        }
        return;
    }
    int c0 = blockIdx.x * 32, jt0 = blockIdx.y * 32;
    int lane = tid & 63, w = tid >> 6;
    int wr = (w >> 1) * 16, wc = (w & 1) * 16;
    int l15 = lane & 15, l4 = lane >> 4;
    stageP<256>(lA, WcatT + l * 262144 + c0 * 256, 256, tid);
    stageP<256>(lB, x16 + jt0 * 256, 256, tid);
    __syncthreads();
    f32x4 a0 = {0.f,0.f,0.f,0.f}, a1 = {0.f,0.f,0.f,0.f};
#pragma unroll
    for (int kc = 0; kc < 8; kc += 2) {
        a0 = __builtin_amdgcn_mfma_f32_16x16x32_bf16(fragP<256>(lA, wr + l15, kc, l4),
                                                     fragP<256>(lB, wc + l15, kc, l4), a0, 0, 0, 0);
        a1 = __builtin_amdgcn_mfma_f32_16x16x32_bf16(fragP<256>(lA, wr + l15, kc + 1, l4),
                                                     fragP<256>(lB, wc + l15, kc + 1, l4), a1, 0, 0, 0);
    }
    f32x4 acc = a0 + a1;
#pragma unroll
    for (int reg = 0; reg < 4; ++reg) {
        int c = c0 + wr + l4 * 4 + reg;
        int j = jt0 + wc + l15;
        supT[c * 512 + j] = f2bf(acc[reg]);
    }
}

// ---------------- c2 (split-k) ----------------
__global__ __launch_bounds__(256) void c2_kernel(const unsigned short* __restrict__ A16,
                                                 const unsigned short* __restrict__ AT16,
                                                 const unsigned short* __restrict__ supT,
                                                 float* __restrict__ Pc2) {
    __shared__ unsigned short lA[64 * 256], lB[64 * 256];
    int i0 = blockIdx.x * 64, f0 = blockIdx.y * 64;
    int s = blockIdx.z, r = s >> 1, kh = s & 1;
    bool bw = (f0 < 128);
    int e0 = bw ? f0 : (f0 - 128);
    const unsigned short* Am = bw ? AT16 : A16;
    int tid = threadIdx.x, lane = tid & 63, w = tid >> 6;
    int wr = (w >> 1) * 32, wc = (w & 1) * 32;
    int l15 = lane & 15, l4 = lane >> 4;
    stage64(lA, Am + (r * 512 + i0) * 512 + kh * 256, 512, tid);
    stage64(lB, supT + ((bw ? 512 : 0) + r * 128 + e0) * 512 + kh * 256, 512, tid);
    __syncthreads();
    f32x4 acc[2][2];
#pragma unroll
    for (int a_ = 0; a_ < 2; ++a_)
#pragma unroll
        for (int b_ = 0; b_ < 2; ++b_) acc[a_][b_] = (f32x4){0.f, 0.f, 0.f, 0.f};
#pragma unroll
    for (int kc = 0; kc < 8; ++kc) {
        bf16x8 af[2], bf_[2];
#pragma unroll
        for (int mb = 0; mb < 2; ++mb) af[mb] = fragP<256>(lA, wr + mb * 16 + l15, kc, l4);
#pragma unroll
        for (int nb = 0; nb < 2; ++nb) bf_[nb] = fragP<256>(lB, wc + nb * 16 + l15, kc, l4);
#pragma unroll
        for (int mb = 0; mb < 2; ++mb)
#pragma unroll
            for (int nb = 0; nb < 2; ++nb)
                acc[mb][nb] = __builtin_amdgcn_mfma_f32_16x16x32_bf16(af[mb], bf_[nb], acc[mb][nb], 0, 0, 0);
    }
    float* dst = Pc2 + s * 131072;
#pragma unroll
    for (int mb = 0; mb < 2; ++mb)
#pragma unroll
        for (int nb = 0; nb < 2; ++nb)
#pragma unroll
            for (int reg = 0; reg < 4; ++reg)
                dst[(i0 + wr + mb * 16 + l4 * 4 + reg) * 256 + f0 + wc + nb * 16 + l15] = acc[mb][nb][reg];
}

// ---------------- c3 ----------------
__global__ __launch_bounds__(256) void c3_kernel(const float* __restrict__ Pc2,
                                                 const float* __restrict__ bsumS,
                                                 const unsigned short* __restrict__ WlinT,
                                                 const float* __restrict__ blin,
                                                 const float* __restrict__ xold,
                                                 float* __restrict__ xnew,
                                                 unsigned short* __restrict__ x16out, int l) {
    __shared__ unsigned short lA[32 * 256], lB[32 * 256];
    int i0 = blockIdx.x * 32, d0 = blockIdx.y * 32;
    int tid = threadIdx.x, lane = tid & 63, w = tid >> 6;
    int wr = (w >> 1) * 16, wc = (w & 1) * 16;
    int l15 = lane & 15, l4 = lane >> 4;
#pragma unroll
    for (int g = 0; g < 4; ++g) {
        int u = g * 256 + tid;
        int row = u >> 5, k8 = (u & 31) * 8;
        float s[8] = {0,0,0,0,0,0,0,0};
#pragma unroll
        for (int s8 = 0; s8 < 8; ++s8) {
            const float4* p = (const float4*)(Pc2 + s8 * 131072 + (i0 + row) * 256 + k8);
            float4 a = p[0], b = p[1];
            s[0] += a.x; s[1] += a.y; s[2] += a.z; s[3] += a.w;
            s[4] += b.x; s[5] += b.y; s[6] += b.z; s[7] += b.w;
        }
        uint4 v;
        unsigned* vp = (unsigned*)&v;
#pragma unroll
        for (int e2 = 0; e2 < 4; ++e2) {
            float lo = fmaxf(s[e2 * 2] + bsumS[l * 256 + k8 + e2 * 2], 0.f);
            float hi = fmaxf(s[e2 * 2 + 1] + bsumS[l * 256 + k8 + e2 * 2 + 1], 0.f);
            vp[e2] = pack2bf(lo, hi);
        }
        *(uint4*)((char*)lA + row * 512 + ((k8 * 2) ^ ((row & 7) << 4))) = v;
    }
    stageP<256>(lB, WlinT + l * 65536 + d0 * 256, 256, tid);
    __syncthreads();
    f32x4 a0 = {0.f,0.f,0.f,0.f}, a1 = {0.f,0.f,0.f,0.f};
#pragma unroll
    for (int kc = 0; kc < 8; kc += 2) {
        a0 = __builtin_amdgcn_mfma_f32_16x16x32_bf16(fragP<256>(lA, wr + l15, kc, l4),
                                                     fragP<256>(lB, wc + l15, kc, l4), a0, 0, 0, 0);
        a1 = __builtin_amdgcn_mfma_f32_16x16x32_bf16(fragP<256>(lA, wr + l15, kc + 1, l4),
                                                     fragP<256>(lB, wc + l15, kc + 1, l4), a1, 0, 0, 0);
    }
    f32x4 acc = a0 + a1;
#pragma unroll
    for (int reg = 0; reg < 4; ++reg) {
        int ii = i0 + wr + l4 * 4 + reg;
        int dd = d0 + wc + l15;
        float vv = acc[reg] + blin[l * 256 + dd] + xold[ii * 256 + dd];
        xnew[ii * 256 + dd] = vv;
        x16out[ii * 256 + dd] = f2bf(vv);
    }
}

extern "C" void kernel_launch(void* const* d_in, const int* in_sizes, int n_in,
                              void* d_out, int out_size, void* d_ws, size_t ws_size,
                              hipStream_t stream) {
    const float* E    = (const float*)d_in[0];
    const float* Wsc0 = (const float*)d_in[1];
    const float* bsc0 = (const float*)d_in[2];
    const float* Wsc1 = (const float*)d_in[3];
    const float* bsc1 = (const float*)d_in[4];
    const float* Wfw  = (const float*)d_in[5];
    const float* bfw  = (const float*)d_in[6];
    const float* Wbw  = (const float*)d_in[7];
    const float* bbw  = (const float*)d_in[8];
    const float* Wlin = (const float*)d_in[9];
    const float* blin = (const float*)d_in[10];
    float* out = (float*)d_out;

    char* ws = (char*)d_ws;
    size_t off = 0;
    unsigned short* E16   = (unsigned short*)(ws + off); off += 512 * 256 * 2;
    unsigned short* W0pA  = (unsigned short*)(ws + off); off += 512 * 256 * 2;
    unsigned short* WabP  = (unsigned short*)(ws + off); off += 1024 * 256 * 2;
    unsigned short* WcatT = (unsigned short*)(ws + off); off += 2 * 1024 * 256 * 2;
    unsigned short* WlinT = (unsigned short*)(ws + off); off += 2 * 256 * 256 * 2;
    float* bsumS          = (float*)(ws + off);          off += 2 * 256 * 4;
    unsigned short* Upk32 = (unsigned short*)(ws + off); off += 512 * 512 * 2;
    float* V              = (float*)(ws + off);          off += 512 * 512 * 4;
    unsigned short* W1A   = (unsigned short*)(ws + off); off += 16 * 2 * 64 * 8 * 2;
    unsigned short* A16   = (unsigned short*)(ws + off); off += 4 * 512 * 512 * 2;
    unsigned short* AT16  = (unsigned short*)(ws + off); off += 4 * 512 * 512 * 2;
    unsigned short* supT  = (unsigned short*)(ws + off); off += 1024 * 512 * 2;
    float* Pc2            = (float*)(ws + off);          off += 8 * 512 * 256 * 4;
    float* xf1            = (float*)(ws + off);          off += 512 * 256 * 4;
    unsigned short* x16_1 = (unsigned short*)(ws + off); off += 512 * 256 * 2;

    prep_kernel<<<512, 512, 0, stream>>>(E, Wsc0, Wsc1, Wfw, bfw, Wbw, bbw, Wlin,
                                         E16, W0pA, WabP, WcatT, WlinT, bsumS, W1A);
    uv_kernel<<<16, 512, 0, stream>>>(E16, WabP, bsc0, Upk32, V);
    pair_kernel<<<dim3(256, 8), 512, 0, stream>>>(E16, W0pA, Upk32, V, W1A, bsc1, A16);

    for (int l = 0; l < 2; ++l) {
        const unsigned short* xin16 = (l == 0) ? E16 : x16_1;
        const float* xoldf = (l == 0) ? E : xf1;
        float* xout = (l == 0) ? xf1 : out;
        c1_kernel<<<dim3(32, (l == 0) ? 24 : 16), 256, 0, stream>>>(WcatT, xin16, supT, A16, AT16, l);
        c2_kernel<<<dim3(8, 4, 8), 256, 0, stream>>>(A16, AT16, supT, Pc2);
        c3_kernel<<<dim3(16, 8), 256, 0, stream>>>(Pc2, bsumS, WlinT, blin, xoldf, xout, x16_1, l);
    }
    (void)in_sizes; (void)n_in; (void)out_size; (void)ws_size;
}